// Round 9
// baseline (885.923 us; speedup 1.0000x reference)
//
#include <hip/hip_runtime.h>
#include <hip/hip_fp16.h>
#include <math.h>

// GCN forward: GCNConv(6->4, self-loops, sym-norm) -> tanh -> mean-pool -> fc1+relu -> fc3
// agg[c] = dinv[c] * ( sum_{edges r->c} p[r] + p[c] ) + conv_b, p[i] = (W x[i]) * dinv[i]
//
// Empirical laws (MI355X, this problem):
//  (1) per-edge divergent gather wall: ~13.4 cy/edge/CU, invariant under occupancy
//      35->75%, table 8/4/2MB, fp32/16/8, LDS layout (R4/R6/R9/R11). MSHR/latency
//      bound; only ELIMINATING the random gather helps.
//  (2) RANDOM global atomics / random scatters = line-granular HBM poison (R8/R10).
//      Sequential-stream writes and coalesced atomics are fine.
//  (3) extra full passes cost 25-180us; minimal pipelines win.
// R12: two-level binning -> gather-free accumulate.
//   k_bin12 (R9-proven): bin by dst>>12 (123 bins), payload (src<<12)|dst_local.
//   k_sort (new): per half-bin, histogram by src-chunk (v>>25, 62 chunks of 8192)
//     + FUSED deg histogram; scan; scatter sorted runs + directory. 62 sequential
//     write streams per block -> L2 write-combines (not R8's random poison).
//   k_node8 (R9-proven): p -> fp8 e4m3 x4 (2MB table).
//   k_acc4 (new): per (partition, half): for each chunk: stage 8192 fp8x4 into LDS
//     (coalesced), process run with p from LDS (NO divergent global reads), SoA S
//     accumulate (R9 zero-conflict layout), coalesced atomic flush to Sg.
//   k_finish8/k_head (R9-proven).
// Tiered: full R11 path (proven 645us) if ws too small for sorted scratch; R1 fallback last.
// R13: identical to R12 — previous round was an infra failure (container died twice);
// kernel audit found no hang/OOB suspects.

constexpr int EPB = 8192;           // edges per k_bin block
constexpr int BINB = 512;           // k_bin block size
constexpr int BT = 512;

// ---- tier-1 (2-level) params ----
constexpr int DPS = 12;             // dst-partition shift (4096 nodes)
constexpr int DP = 1 << DPS;
constexpr unsigned DMASK = DP - 1;
constexpr int NT_MAX = 128;         // k_bin12 scan width (PD = 123)
constexpr int CHS = 13;             // src-chunk shift (8192 nodes)
constexpr int CH = 1 << CHS;
constexpr int NCH_MAX = 64;
constexpr int SPAD = DP + 8;        // SoA channel stride (R9-proven, 0 conflicts)

// ---- tier-2 (R11) params ----
constexpr int NP = 1024;
constexpr int SHIFT = 10;
constexpr unsigned MASK = 1023;
constexpr int NPART_MAX = 512;
constexpr int SPLIT = 4;

struct alignas(8) Half4 { __half2 a, b; };

typedef unsigned u32x4 __attribute__((ext_vector_type(4)));
typedef int      i32x4 __attribute__((ext_vector_type(4)));
typedef float    f32x4 __attribute__((ext_vector_type(4)));
typedef float    f32x2 __attribute__((ext_vector_type(2)));

// =================== tier 1: two-level path ===================

// bin by col>>12; payload = (row<<12)|(col&4095). (R9-proven)
__global__ __launch_bounds__(BINB) void k_bin12(const int* __restrict__ row,
                                                const int* __restrict__ col, int E,
                                                int NT, int cap, int* __restrict__ cursor,
                                                unsigned* __restrict__ binned) {
    __shared__ unsigned lbuf[EPB];
    __shared__ int lcount[NT_MAX];
    __shared__ int lbase[NT_MAX];
    __shared__ int gbase[NT_MAX];
    __shared__ int lpos[NT_MAX];
    __shared__ int sc[NT_MAX];

    int t = threadIdx.x;
    int start = blockIdx.x * EPB;
    int end = min(start + EPB, E);
    bool full = (end - start) == EPB;

    if (t < NT_MAX) { lcount[t] = 0; lpos[t] = 0; }
    __syncthreads();

    if (full) {
        const int4* c4 = (const int4*)(col + start);
#pragma unroll
        for (int i = 0; i < EPB / 4 / BINB; ++i) {
            int4 c = c4[t + i * BINB];
            atomicAdd(&lcount[c.x >> DPS], 1);
            atomicAdd(&lcount[c.y >> DPS], 1);
            atomicAdd(&lcount[c.z >> DPS], 1);
            atomicAdd(&lcount[c.w >> DPS], 1);
        }
    } else {
        for (int e = start + t; e < end; e += BINB)
            atomicAdd(&lcount[col[e] >> DPS], 1);
    }
    __syncthreads();

    if (t < NT_MAX) sc[t] = lcount[t];
    __syncthreads();
    for (int off = 1; off < NT_MAX; off <<= 1) {
        int v = (t >= off && t < NT_MAX) ? sc[t - off] : 0;
        __syncthreads();
        if (t < NT_MAX) sc[t] += v;
        __syncthreads();
    }
    if (t < NT_MAX) lbase[t] = sc[t] - lcount[t];
    if (t < NT) {
        int c = lcount[t];
        gbase[t] = (c > 0) ? atomicAdd(&cursor[t], c) : 0;
    }
    __syncthreads();

    if (full) {
        const int4* c4 = (const int4*)(col + start);
        const i32x4* r4 = (const i32x4*)(row + start);
#pragma unroll
        for (int i = 0; i < EPB / 4 / BINB; ++i) {
            int4 c = c4[t + i * BINB];
            i32x4 r = __builtin_nontemporal_load(&r4[t + i * BINB]);
            int tile, slot;
            tile = c.x >> DPS; slot = atomicAdd(&lpos[tile], 1);
            lbuf[lbase[tile] + slot] = ((unsigned)r.x << DPS) | ((unsigned)c.x & DMASK);
            tile = c.y >> DPS; slot = atomicAdd(&lpos[tile], 1);
            lbuf[lbase[tile] + slot] = ((unsigned)r.y << DPS) | ((unsigned)c.y & DMASK);
            tile = c.z >> DPS; slot = atomicAdd(&lpos[tile], 1);
            lbuf[lbase[tile] + slot] = ((unsigned)r.z << DPS) | ((unsigned)c.z & DMASK);
            tile = c.w >> DPS; slot = atomicAdd(&lpos[tile], 1);
            lbuf[lbase[tile] + slot] = ((unsigned)r.w << DPS) | ((unsigned)c.w & DMASK);
        }
    } else {
        for (int e = start + t; e < end; e += BINB) {
            int r = row[e], c = col[e];
            int tile = c >> DPS;
            int slot = atomicAdd(&lpos[tile], 1);
            lbuf[lbase[tile] + slot] = ((unsigned)r << DPS) | ((unsigned)c & DMASK);
        }
    }
    __syncthreads();

    int lane = t & 63;
    int wave = t >> 6;
    const int nwaves = BINB / 64;
    for (int tile = wave; tile < NT; tile += nwaves) {
        int cnt = lcount[tile];
        if (cnt == 0) continue;
        int lb = lbase[tile];
        int gb = gbase[tile];
        unsigned* dst = binned + (size_t)tile * cap;
        for (int j = lane; j < cnt; j += 64) {
            int slot = gb + j;
            if (slot < cap) __builtin_nontemporal_store(lbuf[lb + j], &dst[slot]);
        }
    }
}

// per half-bin: chunk histogram + FUSED deg histogram, scan, scatter sorted + dir.
// grid = PD*2. Writes are 62 sequential streams/block (L2 write-combined).
__global__ __launch_bounds__(BT) void k_sort(const unsigned* __restrict__ binned,
                                             const int* __restrict__ cursor, int cap,
                                             int n, int nch, int* __restrict__ deg,
                                             unsigned* __restrict__ sorted,
                                             int* __restrict__ dir) {
    __shared__ int hist[NCH_MAX];
    __shared__ int cur[NCH_MAX];
    __shared__ int degs[DP];            // 16 KB
    int part = blockIdx.x >> 1;
    int sub = blockIdx.x & 1;
    int tid = threadIdx.x;
    if (tid < NCH_MAX) hist[tid] = 0;
    for (int i = tid; i < DP; i += BT) degs[i] = 0;
    __syncthreads();

    int cnt = min(cursor[part], cap);
    int half = cnt >> 1;
    int start = sub ? half : 0;
    int endd = sub ? cnt : half;
    const unsigned* bin = binned + (size_t)part * cap;

    // phase A: histograms
    for (int i = start + tid; i < endd; i += BT) {
        unsigned v = bin[i];
        atomicAdd(&hist[v >> 25], 1);
        atomicAdd(&degs[v & DMASK], 1);
    }
    __syncthreads();

    // scan (serial, 62 entries) + directory write + cursor init
    if (tid == 0) {
        int* dd = dir + (part * 2 + sub) * (nch + 1);
        int run = 0;
        for (int c = 0; c < nch; ++c) {
            dd[c] = run;
            cur[c] = run;
            run += hist[c];
        }
        dd[nch] = run;
    }
    __syncthreads();

    // phase B: scatter into sorted runs; payload -> (src_local13 << 12) | dst_local12
    unsigned* out = sorted + (size_t)part * cap + (size_t)sub * (cap >> 1);
    for (int i = start + tid; i < endd; i += BT) {
        unsigned v = bin[i];
        int c = v >> 25;
        int slot = atomicAdd(&cur[c], 1);
        out[slot] = (((v >> DPS) & (CH - 1)) << DPS) | (v & DMASK);
    }

    // deg flush (coalesced global atomics, both subs contribute)
    int base = part * DP;
    for (int i = tid; i < DP; i += BT) {
        int node = base + i;
        if (node < n && degs[i] > 0) atomicAdd(&deg[node], degs[i]);
    }
}

// flat per-node transform: p = (W x) * dinv -> fp8 e4m3 x4 in one u32 (R9-proven)
__global__ __launch_bounds__(256) void k_node8(const float* __restrict__ x,
                                               const float* __restrict__ conv_w,
                                               const int* __restrict__ deg, int n,
                                               unsigned* __restrict__ ph) {
    __shared__ float w[24];
    if (threadIdx.x < 24) w[threadIdx.x] = conv_w[threadIdx.x];
    __syncthreads();
    int i = blockIdx.x * 256 + threadIdx.x;
    if (i >= n) return;
    float dinv = rsqrtf((float)(deg[i] + 1));   // +1 self-loop
    const float* xr = x + (size_t)i * 6;
    float2 a = *(const float2*)xr;
    float2 b = *(const float2*)(xr + 2);
    float2 cc = *(const float2*)(xr + 4);
    float xv[6] = {a.x, a.y, b.x, b.y, cc.x, cc.y};
    float h0 = 0.f, h1 = 0.f, h2 = 0.f, h3 = 0.f;
#pragma unroll
    for (int j = 0; j < 6; ++j) {
        h0 += xv[j] * w[j];
        h1 += xv[j] * w[6 + j];
        h2 += xv[j] * w[12 + j];
        h3 += xv[j] * w[18 + j];
    }
    int pk = 0;
    pk = __builtin_amdgcn_cvt_pk_fp8_f32(h0 * dinv, h1 * dinv, pk, false);
    pk = __builtin_amdgcn_cvt_pk_fp8_f32(h2 * dinv, h3 * dinv, pk, true);
    ph[i] = (unsigned)pk;
}

// gather-free accumulate: per chunk stage 8192 fp8x4 into LDS (coalesced), process
// the chunk's sorted run reading p from LDS; SoA S; coalesced atomic flush to Sg.
__global__ __launch_bounds__(BT) void k_acc4(const unsigned* __restrict__ sorted,
                                             const int* __restrict__ dir, int cap,
                                             const unsigned* __restrict__ ph,
                                             int n, int nch,
                                             float* __restrict__ Sg) {
    __shared__ unsigned stage[CH];      // 32 KB
    __shared__ float S[4 * SPAD];       // 65.7 KB
    int part = blockIdx.x >> 1;
    int sub = blockIdx.x & 1;
    int tid = threadIdx.x;
    for (int i = tid; i < 4 * SPAD; i += BT) S[i] = 0.f;

    const unsigned* src = sorted + (size_t)part * cap + (size_t)sub * (cap >> 1);
    const int* dd = dir + (part * 2 + sub) * (nch + 1);
    __syncthreads();

    for (int c = 0; c < nch; ++c) {
        int cbase = c << CHS;
        int lim = min(CH, n - cbase);
        for (int i = tid; i < lim; i += BT) stage[i] = ph[cbase + i];
        int s0 = dd[c], s1 = dd[c + 1];
        __syncthreads();
        for (int i = s0 + tid; i < s1; i += BT) {
            unsigned w = src[i];
            unsigned p = stage[w >> DPS];       // src_local — LDS, no global gather
            unsigned d = w & DMASK;
            f32x2 lo = __builtin_amdgcn_cvt_pk_f32_fp8((int)p, false);
            f32x2 hi = __builtin_amdgcn_cvt_pk_f32_fp8((int)p, true);
            atomicAdd(&S[d], lo.x);
            atomicAdd(&S[SPAD + d], lo.y);
            atomicAdd(&S[2 * SPAD + d], hi.x);
            atomicAdd(&S[3 * SPAD + d], hi.y);
        }
        __syncthreads();                        // before restaging
    }

    // coalesced flush into per-node float4 Sg (2-way contention)
    int base = part * DP;
    for (int i = tid; i < DP * 4; i += BT) {
        int node = base + (i >> 2);
        if (node < n)
            unsafeAtomicAdd(&Sg[(size_t)base * 4 + i], S[(i & 3) * SPAD + (i >> 2)]);
    }
}

// flat epilogue: tanh(dinv*(S + p) + b), block-reduce -> gsum (R9-proven)
__global__ __launch_bounds__(256) void k_finish8(const float* __restrict__ Sg,
                                                 const unsigned* __restrict__ ph,
                                                 const int* __restrict__ deg,
                                                 const float* __restrict__ conv_b, int n,
                                                 float* __restrict__ gsum) {
    int i = blockIdx.x * 256 + threadIdx.x;
    float4 v = {0.f, 0.f, 0.f, 0.f};
    if (i < n) {
        float dinv = rsqrtf((float)(deg[i] + 1));
        f32x4 s = __builtin_nontemporal_load((const f32x4*)Sg + i);
        unsigned p = ph[i];
        f32x2 lo = __builtin_amdgcn_cvt_pk_f32_fp8((int)p, false);
        f32x2 hi = __builtin_amdgcn_cvt_pk_f32_fp8((int)p, true);
        v.x = tanhf(dinv * (s.x + lo.x) + conv_b[0]);
        v.y = tanhf(dinv * (s.y + lo.y) + conv_b[1]);
        v.z = tanhf(dinv * (s.z + hi.x) + conv_b[2]);
        v.w = tanhf(dinv * (s.w + hi.y) + conv_b[3]);
    }
#pragma unroll
    for (int off = 32; off > 0; off >>= 1) {
        v.x += __shfl_down(v.x, off);
        v.y += __shfl_down(v.y, off);
        v.z += __shfl_down(v.z, off);
        v.w += __shfl_down(v.w, off);
    }
    __shared__ float4 red[4];
    int lane = threadIdx.x & 63, w = threadIdx.x >> 6;
    if (lane == 0) red[w] = v;
    __syncthreads();
    if (threadIdx.x == 0) {
        float4 tt = red[0];
        for (int k = 1; k < 4; ++k) {
            tt.x += red[k].x; tt.y += red[k].y; tt.z += red[k].z; tt.w += red[k].w;
        }
        unsafeAtomicAdd(&gsum[0], tt.x);
        unsafeAtomicAdd(&gsum[1], tt.y);
        unsafeAtomicAdd(&gsum[2], tt.z);
        unsafeAtomicAdd(&gsum[3], tt.w);
    }
}

__global__ void k_head(const float* __restrict__ gsum,
                       const float* __restrict__ fc1w, const float* __restrict__ fc1b,
                       const float* __restrict__ fc3w, const float* __restrict__ fc3b,
                       float* __restrict__ out, int n) {
    __shared__ float hdn[64];
    int t = threadIdx.x;
    float g[4];
    float inv_n = 1.0f / (float)n;
#pragma unroll
    for (int j = 0; j < 4; ++j) g[j] = gsum[j] * inv_n;
    if (t < 64) {
        float a = fc1b[t];
#pragma unroll
        for (int j = 0; j < 4; ++j) a += g[j] * fc1w[t * 4 + j];
        hdn[t] = fmaxf(a, 0.f);
    }
    __syncthreads();
    if (t < 10) {
        float a = fc3b[t];
#pragma unroll
        for (int k = 0; k < 64; ++k) a += hdn[k] * fc3w[t * 64 + k];
        out[t] = a;
    }
}

// =================== tier 2: R11 path (proven 645us) ===================

__global__ __launch_bounds__(BINB) void k_bin10(const int* __restrict__ row,
                                                const int* __restrict__ col, int E,
                                                int P, int cap, int* __restrict__ cursor,
                                                unsigned* __restrict__ binned) {
    __shared__ unsigned lbuf[EPB];
    __shared__ int lcount[NPART_MAX];
    __shared__ int lbase[NPART_MAX];
    __shared__ int gbase[NPART_MAX];
    __shared__ int lpos[NPART_MAX];
    __shared__ int sc[NPART_MAX];

    int t = threadIdx.x;
    int start = blockIdx.x * EPB;
    int end = min(start + EPB, E);
    bool full = (end - start) == EPB;

    lcount[t] = 0; lpos[t] = 0;
    __syncthreads();

    if (full) {
        const int4* c4 = (const int4*)(col + start);
#pragma unroll
        for (int i = 0; i < EPB / 4 / BINB; ++i) {
            int4 c = c4[t + i * BINB];
            atomicAdd(&lcount[c.x >> SHIFT], 1);
            atomicAdd(&lcount[c.y >> SHIFT], 1);
            atomicAdd(&lcount[c.z >> SHIFT], 1);
            atomicAdd(&lcount[c.w >> SHIFT], 1);
        }
    } else {
        for (int e = start + t; e < end; e += BINB)
            atomicAdd(&lcount[col[e] >> SHIFT], 1);
    }
    __syncthreads();

    sc[t] = lcount[t];
    __syncthreads();
    for (int off = 1; off < NPART_MAX; off <<= 1) {
        int v = (t >= off) ? sc[t - off] : 0;
        __syncthreads();
        sc[t] += v;
        __syncthreads();
    }
    lbase[t] = sc[t] - lcount[t];
    if (t < P) {
        int c = lcount[t];
        gbase[t] = (c > 0) ? atomicAdd(&cursor[t], c) : 0;
    }
    __syncthreads();

    if (full) {
        const int4* c4 = (const int4*)(col + start);
        const i32x4* r4 = (const i32x4*)(row + start);
#pragma unroll
        for (int i = 0; i < EPB / 4 / BINB; ++i) {
            int4 c = c4[t + i * BINB];
            i32x4 r = __builtin_nontemporal_load(&r4[t + i * BINB]);
            int part, slot;
            part = c.x >> SHIFT; slot = atomicAdd(&lpos[part], 1);
            lbuf[lbase[part] + slot] = ((unsigned)r.x << SHIFT) | ((unsigned)c.x & MASK);
            part = c.y >> SHIFT; slot = atomicAdd(&lpos[part], 1);
            lbuf[lbase[part] + slot] = ((unsigned)r.y << SHIFT) | ((unsigned)c.y & MASK);
            part = c.z >> SHIFT; slot = atomicAdd(&lpos[part], 1);
            lbuf[lbase[part] + slot] = ((unsigned)r.z << SHIFT) | ((unsigned)c.z & MASK);
            part = c.w >> SHIFT; slot = atomicAdd(&lpos[part], 1);
            lbuf[lbase[part] + slot] = ((unsigned)r.w << SHIFT) | ((unsigned)c.w & MASK);
        }
    } else {
        for (int e = start + t; e < end; e += BINB) {
            int r = row[e], c = col[e];
            int part = c >> SHIFT;
            int slot = atomicAdd(&lpos[part], 1);
            lbuf[lbase[part] + slot] = ((unsigned)r << SHIFT) | ((unsigned)c & MASK);
        }
    }
    __syncthreads();

    int lane = t & 63;
    int wave = t >> 6;
    const int nwaves = BINB / 64;
    for (int part = wave; part < P; part += nwaves) {
        int cnt = lcount[part];
        if (cnt == 0) continue;
        int lb = lbase[part];
        int gb = gbase[part];
        unsigned* dst = binned + (size_t)part * cap;
        for (int j = lane; j < cnt; j += 64) {
            int slot = gb + j;
            if (slot < cap) __builtin_nontemporal_store(lbuf[lb + j], &dst[slot]);
        }
    }
}

__global__ __launch_bounds__(BT) void k_deg_bin(const unsigned* __restrict__ binned,
                                                const int* __restrict__ cursor, int cap,
                                                int n, int* __restrict__ deg) {
    __shared__ int degs[NP];
    int part = blockIdx.x / SPLIT;
    int sub = blockIdx.x - part * SPLIT;
    int tid = threadIdx.x;
    for (int i = tid; i < NP; i += BT) degs[i] = 0;
    __syncthreads();
    int cnt = min(cursor[part], cap);
    const unsigned* bin = binned + (size_t)part * cap;
    const u32x4* bin4 = (const u32x4*)bin;
    int cnt4 = cnt >> 2;
    for (int i = tid + sub * BT; i < cnt4; i += BT * SPLIT) {
        u32x4 v = __builtin_nontemporal_load(&bin4[i]);
        atomicAdd(&degs[v.x & MASK], 1);
        atomicAdd(&degs[v.y & MASK], 1);
        atomicAdd(&degs[v.z & MASK], 1);
        atomicAdd(&degs[v.w & MASK], 1);
    }
    if (sub == 0) {
        for (int e = (cnt4 << 2) + tid; e < cnt; e += BT)
            atomicAdd(&degs[bin[e] & MASK], 1);
    }
    __syncthreads();
    int base = part * NP;
    for (int i = tid; i < NP; i += BT) {
        int node = base + i;
        if (node < n && degs[i] > 0) atomicAdd(&deg[node], degs[i]);
    }
}

__global__ __launch_bounds__(256) void k_node2h(const float* __restrict__ x,
                                                const float* __restrict__ conv_w,
                                                const int* __restrict__ deg, int n,
                                                Half4* __restrict__ ph,
                                                float* __restrict__ dinvg) {
    __shared__ float w[24];
    if (threadIdx.x < 24) w[threadIdx.x] = conv_w[threadIdx.x];
    __syncthreads();
    int i = blockIdx.x * 256 + threadIdx.x;
    if (i >= n) return;
    float dinv = rsqrtf((float)(deg[i] + 1));
    const float* xr = x + (size_t)i * 6;
    float2 a = *(const float2*)xr;
    float2 b = *(const float2*)(xr + 2);
    float2 cc = *(const float2*)(xr + 4);
    float xv[6] = {a.x, a.y, b.x, b.y, cc.x, cc.y};
    float h0 = 0.f, h1 = 0.f, h2 = 0.f, h3 = 0.f;
#pragma unroll
    for (int j = 0; j < 6; ++j) {
        h0 += xv[j] * w[j];
        h1 += xv[j] * w[6 + j];
        h2 += xv[j] * w[12 + j];
        h3 += xv[j] * w[18 + j];
    }
    Half4 o;
    o.a = __floats2half2_rn(h0 * dinv, h1 * dinv);
    o.b = __floats2half2_rn(h2 * dinv, h3 * dinv);
    ph[i] = o;
    dinvg[i] = dinv;
}

__global__ __launch_bounds__(BT) void k_acc(const unsigned* __restrict__ binned,
                                            const int* __restrict__ cursor, int cap,
                                            const Half4* __restrict__ ph,
                                            const float* __restrict__ dinvg,
                                            const float* __restrict__ conv_b, int n,
                                            float* __restrict__ gsum) {
    __shared__ float S[NP * 5];
    __shared__ float4 red[BT / 64];
    int part = blockIdx.x;
    int tid = threadIdx.x;
    for (int i = tid; i < NP * 5; i += BT) S[i] = 0.f;
    __syncthreads();
    int cnt = min(cursor[part], cap);
    const unsigned* bin = binned + (size_t)part * cap;
    const u32x4* bin4 = (const u32x4*)bin;
    int cnt4 = cnt >> 2;
    for (int i = tid; i < cnt4; i += BT) {
        u32x4 v = __builtin_nontemporal_load(&bin4[i]);
        Half4 h0 = ph[v.x >> SHIFT];
        Half4 h1 = ph[v.y >> SHIFT];
        Half4 h2 = ph[v.z >> SHIFT];
        Half4 h3 = ph[v.w >> SHIFT];
        float2 a, b; float* s;
        a = __half22float2(h0.a); b = __half22float2(h0.b); s = &S[(v.x & MASK) * 5];
        atomicAdd(s + 0, a.x); atomicAdd(s + 1, a.y); atomicAdd(s + 2, b.x); atomicAdd(s + 3, b.y);
        a = __half22float2(h1.a); b = __half22float2(h1.b); s = &S[(v.y & MASK) * 5];
        atomicAdd(s + 0, a.x); atomicAdd(s + 1, a.y); atomicAdd(s + 2, b.x); atomicAdd(s + 3, b.y);
        a = __half22float2(h2.a); b = __half22float2(h2.b); s = &S[(v.z & MASK) * 5];
        atomicAdd(s + 0, a.x); atomicAdd(s + 1, a.y); atomicAdd(s + 2, b.x); atomicAdd(s + 3, b.y);
        a = __half22float2(h3.a); b = __half22float2(h3.b); s = &S[(v.w & MASK) * 5];
        atomicAdd(s + 0, a.x); atomicAdd(s + 1, a.y); atomicAdd(s + 2, b.x); atomicAdd(s + 3, b.y);
    }
    for (int e = (cnt4 << 2) + tid; e < cnt; e += BT) {
        unsigned v = bin[e];
        Half4 h = ph[v >> SHIFT];
        float2 a = __half22float2(h.a), b = __half22float2(h.b);
        float* s = &S[(v & MASK) * 5];
        atomicAdd(s + 0, a.x); atomicAdd(s + 1, a.y); atomicAdd(s + 2, b.x); atomicAdd(s + 3, b.y);
    }
    __syncthreads();
    float b0 = conv_b[0], b1 = conv_b[1], b2 = conv_b[2], b3 = conv_b[3];
    float4 acc = {0.f, 0.f, 0.f, 0.f};
    int base = part * NP;
    for (int i = tid; i < NP; i += BT) {
        int node = base + i;
        if (node >= n) continue;
        float di = dinvg[node];
        Half4 hp = ph[node];
        float2 pa = __half22float2(hp.a), pb = __half22float2(hp.b);
        acc.x += tanhf(di * (S[i * 5 + 0] + pa.x) + b0);
        acc.y += tanhf(di * (S[i * 5 + 1] + pa.y) + b1);
        acc.z += tanhf(di * (S[i * 5 + 2] + pb.x) + b2);
        acc.w += tanhf(di * (S[i * 5 + 3] + pb.y) + b3);
    }
#pragma unroll
    for (int off = 32; off > 0; off >>= 1) {
        acc.x += __shfl_down(acc.x, off);
        acc.y += __shfl_down(acc.y, off);
        acc.z += __shfl_down(acc.z, off);
        acc.w += __shfl_down(acc.w, off);
    }
    int lane = tid & 63, wv = tid >> 6;
    if (lane == 0) red[wv] = acc;
    __syncthreads();
    if (tid == 0) {
        float4 tt = red[0];
        for (int k = 1; k < BT / 64; ++k) {
            tt.x += red[k].x; tt.y += red[k].y; tt.z += red[k].z; tt.w += red[k].w;
        }
        unsafeAtomicAdd(&gsum[0], tt.x);
        unsafeAtomicAdd(&gsum[1], tt.y);
        unsafeAtomicAdd(&gsum[2], tt.z);
        unsafeAtomicAdd(&gsum[3], tt.w);
    }
}

// =================== tier 3: round-1 fallback ===================

__global__ void k_deg(const int* __restrict__ col, int n_edges, int* __restrict__ deg) {
    int t = blockIdx.x * blockDim.x + threadIdx.x;
    int base = t * 4;
    if (base + 4 <= n_edges) {
        int4 c = *(const int4*)(col + base);
        atomicAdd(&deg[c.x], 1); atomicAdd(&deg[c.y], 1);
        atomicAdd(&deg[c.z], 1); atomicAdd(&deg[c.w], 1);
    } else {
        for (int e = base; e < n_edges; ++e) atomicAdd(&deg[col[e]], 1);
    }
}

__global__ void k_node(const float* __restrict__ x, const float* __restrict__ conv_w,
                       const int* __restrict__ deg, float4* __restrict__ p, int n) {
    int i = blockIdx.x * blockDim.x + threadIdx.x;
    if (i >= n) return;
    const float* xr = x + (size_t)i * 6;
    float2 a = *(const float2*)xr;
    float2 b = *(const float2*)(xr + 2);
    float2 c = *(const float2*)(xr + 4);
    float xv[6] = {a.x, a.y, b.x, b.y, c.x, c.y};
    float dinv = rsqrtf((float)(deg[i] + 1));
    float h0 = 0.f, h1 = 0.f, h2 = 0.f, h3 = 0.f;
#pragma unroll
    for (int j = 0; j < 6; ++j) {
        h0 += xv[j] * conv_w[j];
        h1 += xv[j] * conv_w[6 + j];
        h2 += xv[j] * conv_w[12 + j];
        h3 += xv[j] * conv_w[18 + j];
    }
    float4 o; o.x = h0 * dinv; o.y = h1 * dinv; o.z = h2 * dinv; o.w = h3 * dinv;
    p[i] = o;
}

__global__ void k_scatter(const int* __restrict__ row, const int* __restrict__ col, int n_edges,
                          const float4* __restrict__ p, float* __restrict__ S) {
    int t = blockIdx.x * blockDim.x + threadIdx.x;
    int base = t * 2;
    if (base + 2 <= n_edges) {
        int2 r = *(const int2*)(row + base);
        int2 c = *(const int2*)(col + base);
        float4 p0 = p[r.x], p1 = p[r.y];
        float* s0 = S + 4 * c.x;
        unsafeAtomicAdd(s0 + 0, p0.x); unsafeAtomicAdd(s0 + 1, p0.y);
        unsafeAtomicAdd(s0 + 2, p0.z); unsafeAtomicAdd(s0 + 3, p0.w);
        float* s1 = S + 4 * c.y;
        unsafeAtomicAdd(s1 + 0, p1.x); unsafeAtomicAdd(s1 + 1, p1.y);
        unsafeAtomicAdd(s1 + 2, p1.z); unsafeAtomicAdd(s1 + 3, p1.w);
    } else {
        for (int e = base; e < n_edges; ++e) {
            int r = row[e], c = col[e];
            float4 pv = p[r];
            float* s = S + 4 * c;
            unsafeAtomicAdd(s + 0, pv.x); unsafeAtomicAdd(s + 1, pv.y);
            unsafeAtomicAdd(s + 2, pv.z); unsafeAtomicAdd(s + 3, pv.w);
        }
    }
}

__global__ void k_reduce(const float4* __restrict__ S4, const float4* __restrict__ p,
                         const int* __restrict__ deg, const float* __restrict__ conv_b,
                         int n, float* __restrict__ gsum) {
    int i = blockIdx.x * blockDim.x + threadIdx.x;
    float4 v = {0.f, 0.f, 0.f, 0.f};
    if (i < n) {
        float dinv = rsqrtf((float)(deg[i] + 1));
        float4 s = S4[i];
        float4 pp = p[i];
        v.x = tanhf(dinv * (s.x + pp.x) + conv_b[0]);
        v.y = tanhf(dinv * (s.y + pp.y) + conv_b[1]);
        v.z = tanhf(dinv * (s.z + pp.z) + conv_b[2]);
        v.w = tanhf(dinv * (s.w + pp.w) + conv_b[3]);
    }
#pragma unroll
    for (int off = 32; off > 0; off >>= 1) {
        v.x += __shfl_down(v.x, off);
        v.y += __shfl_down(v.y, off);
        v.z += __shfl_down(v.z, off);
        v.w += __shfl_down(v.w, off);
    }
    __shared__ float4 lds[4];
    int lane = threadIdx.x & 63, w = threadIdx.x >> 6;
    if (lane == 0) lds[w] = v;
    __syncthreads();
    if (threadIdx.x == 0) {
        float4 tt = lds[0];
        for (int k = 1; k < 4; ++k) {
            tt.x += lds[k].x; tt.y += lds[k].y; tt.z += lds[k].z; tt.w += lds[k].w;
        }
        unsafeAtomicAdd(&gsum[0], tt.x); unsafeAtomicAdd(&gsum[1], tt.y);
        unsafeAtomicAdd(&gsum[2], tt.z); unsafeAtomicAdd(&gsum[3], tt.w);
    }
}

// ---------------- launch ----------------

extern "C" void kernel_launch(void* const* d_in, const int* in_sizes, int n_in,
                              void* d_out, int out_size, void* d_ws, size_t ws_size,
                              hipStream_t stream) {
    const float* x      = (const float*)d_in[0];
    const int*   ei     = (const int*)d_in[1];
    const float* conv_w = (const float*)d_in[2];
    const float* conv_b = (const float*)d_in[3];
    const float* fc1w   = (const float*)d_in[4];
    const float* fc1b   = (const float*)d_in[5];
    const float* fc3w   = (const float*)d_in[6];
    const float* fc3b   = (const float*)d_in[7];

    int n = in_sizes[0] / 6;
    int E = in_sizes[1] / 2;
    const int* row = ei;       // edge_index[0] = source
    const int* col = ei + E;   // edge_index[1] = target

    char* ws = (char*)d_ws;

    // ---- tier 1 layout: 2-level path ----
    {
        int PD = (n + DP - 1) / DP;
        int nch = (n + CH - 1) >> CHS;
        int avg = (E + PD - 1) / PD;
        int cap = ((avg + avg / 64 + 3072) + 15) & ~15;

        size_t off = 0;
        size_t cursor_off = off;      off += (size_t)NT_MAX * sizeof(int);
        size_t gsum_off = off;        off += 4 * sizeof(float);
        off = (off + 15) & ~(size_t)15;
        size_t deg_off = off;         off += (size_t)n * sizeof(int);
        off = (off + 15) & ~(size_t)15;
        size_t S_off = off;           off += (size_t)n * 4 * sizeof(float);
        size_t zero_end = off;
        off = (off + 15) & ~(size_t)15;
        size_t ph_off = off;          off += (size_t)n * sizeof(unsigned);
        off = (off + 15) & ~(size_t)15;
        size_t bin_off = off;         off += (size_t)PD * cap * sizeof(unsigned);
        off = (off + 15) & ~(size_t)15;
        size_t sort_off = off;        off += (size_t)PD * cap * sizeof(unsigned);
        off = (off + 15) & ~(size_t)15;
        size_t dir_off = off;         off += (size_t)PD * 2 * (nch + 1) * sizeof(int);
        size_t need1 = off;

        if (ws_size >= need1 && n <= (1 << 19) && PD <= NT_MAX && nch <= NCH_MAX) {
            int* cursor = (int*)(ws + cursor_off);
            float* gsum = (float*)(ws + gsum_off);
            int* deg = (int*)(ws + deg_off);
            float* Sg = (float*)(ws + S_off);
            unsigned* ph = (unsigned*)(ws + ph_off);
            unsigned* binned = (unsigned*)(ws + bin_off);
            unsigned* sorted = (unsigned*)(ws + sort_off);
            int* dir = (int*)(ws + dir_off);

            hipMemsetAsync(d_ws, 0, zero_end, stream);
            int bin_blocks = (E + EPB - 1) / EPB;
            k_bin12<<<bin_blocks, BINB, 0, stream>>>(row, col, E, PD, cap, cursor, binned);
            k_sort<<<PD * 2, BT, 0, stream>>>(binned, cursor, cap, n, nch, deg, sorted, dir);
            k_node8<<<(n + 255) / 256, 256, 0, stream>>>(x, conv_w, deg, n, ph);
            k_acc4<<<PD * 2, BT, 0, stream>>>(sorted, dir, cap, ph, n, nch, Sg);
            k_finish8<<<(n + 255) / 256, 256, 0, stream>>>(Sg, ph, deg, conv_b, n, gsum);
            k_head<<<1, 64, 0, stream>>>(gsum, fc1w, fc1b, fc3w, fc3b, (float*)d_out, n);
            return;
        }
    }

    // ---- tier 2 layout: R11 path ----
    {
        int P = (n + NP - 1) / NP;
        int avg = (E + P - 1) / P;
        int cap = ((avg + avg / 32 + 1024) + 15) & ~15;

        size_t off = 0;
        size_t cursor_off = off;      off += (size_t)P * sizeof(int);
        off = (off + 15) & ~(size_t)15;
        size_t gsum_off = off;        off += 4 * sizeof(float);
        off = (off + 15) & ~(size_t)15;
        size_t deg_off = off;         off += (size_t)n * sizeof(int);
        size_t zero_end = off;
        off = (off + 15) & ~(size_t)15;
        size_t dinv_off = off;        off += (size_t)n * sizeof(float);
        off = (off + 15) & ~(size_t)15;
        size_t ph_off = off;          off += (size_t)n * sizeof(Half4);
        off = (off + 15) & ~(size_t)15;
        size_t bin_off = off;         off += (size_t)P * cap * sizeof(unsigned);
        size_t need2 = off;

        if (ws_size >= need2 && P <= NPART_MAX && n < (1 << 21)) {
            int* cursor = (int*)(ws + cursor_off);
            float* gsum = (float*)(ws + gsum_off);
            int* deg = (int*)(ws + deg_off);
            float* dinvg = (float*)(ws + dinv_off);
            Half4* ph = (Half4*)(ws + ph_off);
            unsigned* binned = (unsigned*)(ws + bin_off);

            hipMemsetAsync(d_ws, 0, zero_end, stream);
            int bin_blocks = (E + EPB - 1) / EPB;
            k_bin10<<<bin_blocks, BINB, 0, stream>>>(row, col, E, P, cap, cursor, binned);
            k_deg_bin<<<P * SPLIT, BT, 0, stream>>>(binned, cursor, cap, n, deg);
            k_node2h<<<(n + 255) / 256, 256, 0, stream>>>(x, conv_w, deg, n, ph, dinvg);
            k_acc<<<P, BT, 0, stream>>>(binned, cursor, cap, ph, dinvg, conv_b, n, gsum);
            k_head<<<1, 64, 0, stream>>>(gsum, fc1w, fc1b, fc3w, fc3b, (float*)d_out, n);
            return;
        }
    }

    // ---- tier 3: fallback ----
    {
        size_t o = 0;
        int* deg = (int*)(ws + o);      o += (size_t)n * sizeof(int);
        o = (o + 15) & ~(size_t)15;
        float* S = (float*)(ws + o);    o += (size_t)n * 4 * sizeof(float);
        float* gsum = (float*)(ws + o);
        size_t zend = o + 4 * sizeof(float);
        o = (zend + 15) & ~(size_t)15;
        float4* p = (float4*)(ws + o);

        hipMemsetAsync(d_ws, 0, zend, stream);
        int t1 = (E + 3) / 4;
        k_deg<<<(t1 + 255) / 256, 256, 0, stream>>>(col, E, deg);
        k_node<<<(n + 255) / 256, 256, 0, stream>>>(x, conv_w, deg, p, n);
        int t3 = (E + 1) / 2;
        k_scatter<<<(t3 + 255) / 256, 256, 0, stream>>>(row, col, E, p, S);
        k_reduce<<<(n + 255) / 256, 256, 0, stream>>>((const float4*)S, p, deg, conv_b, n, gsum);
        k_head<<<1, 64, 0, stream>>>(gsum, fc1w, fc1b, fc3w, fc3b, (float*)d_out, n);
    }
}

// Round 10
// 624.668 us; speedup vs baseline: 1.4182x; 1.4182x over previous
//
#include <hip/hip_runtime.h>
#include <hip/hip_fp16.h>
#include <math.h>

// GCN forward: GCNConv(6->4, self-loops, sym-norm) -> tanh -> mean-pool -> fc1+relu -> fc3
// agg[c] = dinv[c] * ( sum_{edges r->c} p[r] + p[c] ) + conv_b, p[i] = (W x[i]) * dinv[i]
//
// R14 = exact revert to the session-best R0 kernel (624.0 us proven).
// Session ledger (laws, MI355X):
//  (1) accumulate wall: 13-16 cy/edge across FIVE structures (global-gather fp32/16/8,
//      SoA tile, LDS-staged gather-free) — invariant under occupancy 35->75%, table
//      8/4/2MB, LDS layout. Latency/issue-bound; no PMC pipe >6%.
//  (2) RANDOM global atomics = line-granular HBM poison (R8: 2.1GB/3.1ms; R10: 590MB).
//  (3) extra passes cost 25-180us; this minimal 4-kernel pipeline beat every
//      fancier structure (624 vs 645/751/772/885/1263/4111).
//  (4) LDS-staged gather needs run >= chunk (grid*n <= E); with E/n=32 unsatisfiable
//      at useful grid sizes (R13: 0.13 reuse -> staging cost == gather cost).

constexpr int NP = 1024;        // nodes per partition
constexpr int SHIFT = 10;
constexpr unsigned MASK = 1023;
constexpr int NPART_MAX = 512;  // scan width; P = ceil(500k/1024) = 489
constexpr int EPB = 8192;       // edges per k_bin block
constexpr int BINB = 512;       // k_bin block size
constexpr int BT = 512;         // per-partition kernel block size

struct alignas(8) Half4 { __half2 a, b; };

// ---------------- binning path ----------------

__global__ __launch_bounds__(BINB) void k_bin(const int* __restrict__ row,
                                              const int* __restrict__ col, int E,
                                              int P, int cap, int* __restrict__ cursor,
                                              unsigned* __restrict__ binned) {
    __shared__ unsigned lbuf[EPB];          // 32 KB, sorted-by-partition edge buffer
    __shared__ int lcount[NPART_MAX];
    __shared__ int lbase[NPART_MAX];
    __shared__ int gbase[NPART_MAX];
    __shared__ int lpos[NPART_MAX];
    __shared__ int sc[NPART_MAX];

    int t = threadIdx.x;
    int start = blockIdx.x * EPB;
    int end = min(start + EPB, E);
    bool full = (end - start) == EPB;

    lcount[t] = 0; lpos[t] = 0;
    __syncthreads();

    // phase 1: count per partition (vectorized)
    if (full) {
        const int4* c4 = (const int4*)(col + start);
#pragma unroll
        for (int i = 0; i < EPB / 4 / BINB; ++i) {
            int4 c = c4[t + i * BINB];
            atomicAdd(&lcount[c.x >> SHIFT], 1);
            atomicAdd(&lcount[c.y >> SHIFT], 1);
            atomicAdd(&lcount[c.z >> SHIFT], 1);
            atomicAdd(&lcount[c.w >> SHIFT], 1);
        }
    } else {
        for (int e = start + t; e < end; e += BINB)
            atomicAdd(&lcount[col[e] >> SHIFT], 1);
    }
    __syncthreads();

    // phase 2: exclusive scan (Hillis-Steele, 512 wide)
    sc[t] = lcount[t];
    __syncthreads();
    for (int off = 1; off < NPART_MAX; off <<= 1) {
        int v = (t >= off) ? sc[t - off] : 0;
        __syncthreads();
        sc[t] += v;
        __syncthreads();
    }
    lbase[t] = sc[t] - lcount[t];
    if (t < P) {
        int c = lcount[t];
        gbase[t] = (c > 0) ? atomicAdd(&cursor[t], c) : 0;
    }
    __syncthreads();

    // phase 3: place edges into LDS sorted by partition
    if (full) {
        const int4* c4 = (const int4*)(col + start);
        const int4* r4 = (const int4*)(row + start);
#pragma unroll
        for (int i = 0; i < EPB / 4 / BINB; ++i) {
            int4 c = c4[t + i * BINB];
            int4 r = r4[t + i * BINB];
            int part, slot;
            part = c.x >> SHIFT; slot = atomicAdd(&lpos[part], 1);
            lbuf[lbase[part] + slot] = ((unsigned)r.x << SHIFT) | ((unsigned)c.x & MASK);
            part = c.y >> SHIFT; slot = atomicAdd(&lpos[part], 1);
            lbuf[lbase[part] + slot] = ((unsigned)r.y << SHIFT) | ((unsigned)c.y & MASK);
            part = c.z >> SHIFT; slot = atomicAdd(&lpos[part], 1);
            lbuf[lbase[part] + slot] = ((unsigned)r.z << SHIFT) | ((unsigned)c.z & MASK);
            part = c.w >> SHIFT; slot = atomicAdd(&lpos[part], 1);
            lbuf[lbase[part] + slot] = ((unsigned)r.w << SHIFT) | ((unsigned)c.w & MASK);
        }
    } else {
        for (int e = start + t; e < end; e += BINB) {
            int r = row[e], c = col[e];
            int part = c >> SHIFT;
            int slot = atomicAdd(&lpos[part], 1);
            lbuf[lbase[part] + slot] = ((unsigned)r << SHIFT) | ((unsigned)c & MASK);
        }
    }
    __syncthreads();

    // phase 4: coalesced flush, one wave per partition round-robin
    int lane = t & 63;
    int wave = t >> 6;
    const int nwaves = BINB / 64;
    for (int part = wave; part < P; part += nwaves) {
        int cnt = lcount[part];
        if (cnt == 0) continue;
        int lb = lbase[part];
        int gb = gbase[part];
        unsigned* dst = binned + (size_t)part * cap;
        for (int j = lane; j < cnt; j += 64) {
            int slot = gb + j;
            if (slot < cap) dst[slot] = lbuf[lb + j];
        }
    }
}

// per-partition: deg from bin (LDS), then p = (W x)*dinv -> fp16x4, store dinv
__global__ __launch_bounds__(BT) void k_part_node(const unsigned* __restrict__ binned,
                                                  const int* __restrict__ cursor, int cap,
                                                  const float* __restrict__ x,
                                                  const float* __restrict__ conv_w, int n,
                                                  Half4* __restrict__ ph,
                                                  float* __restrict__ dinvg) {
    __shared__ int degs[NP];
    __shared__ float w[24];
    int part = blockIdx.x;
    int tid = threadIdx.x;
    if (tid < 24) w[tid] = conv_w[tid];
    for (int i = tid; i < NP; i += BT) degs[i] = 0;
    __syncthreads();
    int cnt = min(cursor[part], cap);
    const unsigned* bin = binned + (size_t)part * cap;
    const uint4* bin4 = (const uint4*)bin;
    int cnt4 = cnt >> 2;
    for (int i = tid; i < cnt4; i += BT) {
        uint4 v = bin4[i];
        atomicAdd(&degs[v.x & MASK], 1);
        atomicAdd(&degs[v.y & MASK], 1);
        atomicAdd(&degs[v.z & MASK], 1);
        atomicAdd(&degs[v.w & MASK], 1);
    }
    for (int e = (cnt4 << 2) + tid; e < cnt; e += BT)
        atomicAdd(&degs[bin[e] & MASK], 1);
    __syncthreads();
    int base = part * NP;
    for (int i = tid; i < NP; i += BT) {
        int node = base + i;
        if (node >= n) continue;
        float dinv = rsqrtf((float)(degs[i] + 1));   // +1 self-loop
        const float* xr = x + (size_t)node * 6;
        float2 a = *(const float2*)xr;
        float2 b = *(const float2*)(xr + 2);
        float2 cc = *(const float2*)(xr + 4);
        float xv[6] = {a.x, a.y, b.x, b.y, cc.x, cc.y};
        float h0 = 0.f, h1 = 0.f, h2 = 0.f, h3 = 0.f;
#pragma unroll
        for (int j = 0; j < 6; ++j) {
            h0 += xv[j] * w[j];
            h1 += xv[j] * w[6 + j];
            h2 += xv[j] * w[12 + j];
            h3 += xv[j] * w[18 + j];
        }
        Half4 o;
        o.a = __floats2half2_rn(h0 * dinv, h1 * dinv);
        o.b = __floats2half2_rn(h2 * dinv, h3 * dinv);
        ph[node] = o;
        dinvg[node] = dinv;
    }
}

// per-partition: accumulate p[row] into LDS tile (stride 5), tanh, block-reduce -> gsum
__global__ __launch_bounds__(BT) void k_acc(const unsigned* __restrict__ binned,
                                            const int* __restrict__ cursor, int cap,
                                            const Half4* __restrict__ ph,
                                            const float* __restrict__ dinvg,
                                            const float* __restrict__ conv_b, int n,
                                            float* __restrict__ gsum) {
    __shared__ float S[NP * 5];          // 20 KB, stride 5 (coprime with 32 banks)
    __shared__ float4 red[BT / 64];
    int part = blockIdx.x;
    int tid = threadIdx.x;
    for (int i = tid; i < NP * 5; i += BT) S[i] = 0.f;
    __syncthreads();
    int cnt = min(cursor[part], cap);
    const unsigned* bin = binned + (size_t)part * cap;
    const uint4* bin4 = (const uint4*)bin;
    int cnt4 = cnt >> 2;
    for (int i = tid; i < cnt4; i += BT) {
        uint4 v = bin4[i];
        Half4 h0 = ph[v.x >> SHIFT];   // 4 independent 8 B gathers in flight
        Half4 h1 = ph[v.y >> SHIFT];
        Half4 h2 = ph[v.z >> SHIFT];
        Half4 h3 = ph[v.w >> SHIFT];
        float2 a, b; float* s;
        a = __half22float2(h0.a); b = __half22float2(h0.b); s = &S[(v.x & MASK) * 5];
        atomicAdd(s + 0, a.x); atomicAdd(s + 1, a.y); atomicAdd(s + 2, b.x); atomicAdd(s + 3, b.y);
        a = __half22float2(h1.a); b = __half22float2(h1.b); s = &S[(v.y & MASK) * 5];
        atomicAdd(s + 0, a.x); atomicAdd(s + 1, a.y); atomicAdd(s + 2, b.x); atomicAdd(s + 3, b.y);
        a = __half22float2(h2.a); b = __half22float2(h2.b); s = &S[(v.z & MASK) * 5];
        atomicAdd(s + 0, a.x); atomicAdd(s + 1, a.y); atomicAdd(s + 2, b.x); atomicAdd(s + 3, b.y);
        a = __half22float2(h3.a); b = __half22float2(h3.b); s = &S[(v.w & MASK) * 5];
        atomicAdd(s + 0, a.x); atomicAdd(s + 1, a.y); atomicAdd(s + 2, b.x); atomicAdd(s + 3, b.y);
    }
    for (int e = (cnt4 << 2) + tid; e < cnt; e += BT) {
        unsigned v = bin[e];
        Half4 h = ph[v >> SHIFT];
        float2 a = __half22float2(h.a), b = __half22float2(h.b);
        float* s = &S[(v & MASK) * 5];
        atomicAdd(s + 0, a.x); atomicAdd(s + 1, a.y); atomicAdd(s + 2, b.x); atomicAdd(s + 3, b.y);
    }
    __syncthreads();
    float b0 = conv_b[0], b1 = conv_b[1], b2 = conv_b[2], b3 = conv_b[3];
    float4 acc = {0.f, 0.f, 0.f, 0.f};
    int base = part * NP;
    for (int i = tid; i < NP; i += BT) {
        int node = base + i;
        if (node >= n) continue;
        float di = dinvg[node];
        Half4 hp = ph[node];
        float2 pa = __half22float2(hp.a), pb = __half22float2(hp.b);
        acc.x += tanhf(di * (S[i * 5 + 0] + pa.x) + b0);
        acc.y += tanhf(di * (S[i * 5 + 1] + pa.y) + b1);
        acc.z += tanhf(di * (S[i * 5 + 2] + pb.x) + b2);
        acc.w += tanhf(di * (S[i * 5 + 3] + pb.y) + b3);
    }
#pragma unroll
    for (int off = 32; off > 0; off >>= 1) {
        acc.x += __shfl_down(acc.x, off);
        acc.y += __shfl_down(acc.y, off);
        acc.z += __shfl_down(acc.z, off);
        acc.w += __shfl_down(acc.w, off);
    }
    int lane = tid & 63, wv = tid >> 6;
    if (lane == 0) red[wv] = acc;
    __syncthreads();
    if (tid == 0) {
        float4 tt = red[0];
        for (int k = 1; k < BT / 64; ++k) {
            tt.x += red[k].x; tt.y += red[k].y; tt.z += red[k].z; tt.w += red[k].w;
        }
        unsafeAtomicAdd(&gsum[0], tt.x);
        unsafeAtomicAdd(&gsum[1], tt.y);
        unsafeAtomicAdd(&gsum[2], tt.z);
        unsafeAtomicAdd(&gsum[3], tt.w);
    }
}

__global__ void k_head(const float* __restrict__ gsum,
                       const float* __restrict__ fc1w, const float* __restrict__ fc1b,
                       const float* __restrict__ fc3w, const float* __restrict__ fc3b,
                       float* __restrict__ out, int n) {
    __shared__ float hdn[64];
    int t = threadIdx.x;
    float g[4];
    float inv_n = 1.0f / (float)n;
#pragma unroll
    for (int j = 0; j < 4; ++j) g[j] = gsum[j] * inv_n;
    if (t < 64) {
        float a = fc1b[t];
#pragma unroll
        for (int j = 0; j < 4; ++j) a += g[j] * fc1w[t * 4 + j];
        hdn[t] = fmaxf(a, 0.f);
    }
    __syncthreads();
    if (t < 10) {
        float a = fc3b[t];
#pragma unroll
        for (int k = 0; k < 64; ++k) a += hdn[k] * fc3w[t * 64 + k];
        out[t] = a;
    }
}

// ---------------- fallback path (round-1, global atomics) ----------------

__global__ void k_deg(const int* __restrict__ col, int n_edges, int* __restrict__ deg) {
    int t = blockIdx.x * blockDim.x + threadIdx.x;
    int base = t * 4;
    if (base + 4 <= n_edges) {
        int4 c = *(const int4*)(col + base);
        atomicAdd(&deg[c.x], 1); atomicAdd(&deg[c.y], 1);
        atomicAdd(&deg[c.z], 1); atomicAdd(&deg[c.w], 1);
    } else {
        for (int e = base; e < n_edges; ++e) atomicAdd(&deg[col[e]], 1);
    }
}

__global__ void k_node(const float* __restrict__ x, const float* __restrict__ conv_w,
                       const int* __restrict__ deg, float4* __restrict__ p, int n) {
    int i = blockIdx.x * blockDim.x + threadIdx.x;
    if (i >= n) return;
    const float* xr = x + (size_t)i * 6;
    float2 a = *(const float2*)xr;
    float2 b = *(const float2*)(xr + 2);
    float2 c = *(const float2*)(xr + 4);
    float xv[6] = {a.x, a.y, b.x, b.y, c.x, c.y};
    float dinv = rsqrtf((float)(deg[i] + 1));
    float h0 = 0.f, h1 = 0.f, h2 = 0.f, h3 = 0.f;
#pragma unroll
    for (int j = 0; j < 6; ++j) {
        h0 += xv[j] * conv_w[j];
        h1 += xv[j] * conv_w[6 + j];
        h2 += xv[j] * conv_w[12 + j];
        h3 += xv[j] * conv_w[18 + j];
    }
    float4 o; o.x = h0 * dinv; o.y = h1 * dinv; o.z = h2 * dinv; o.w = h3 * dinv;
    p[i] = o;
}

__global__ void k_scatter(const int* __restrict__ row, const int* __restrict__ col, int n_edges,
                          const float4* __restrict__ p, float* __restrict__ S) {
    int t = blockIdx.x * blockDim.x + threadIdx.x;
    int base = t * 2;
    if (base + 2 <= n_edges) {
        int2 r = *(const int2*)(row + base);
        int2 c = *(const int2*)(col + base);
        float4 p0 = p[r.x], p1 = p[r.y];
        float* s0 = S + 4 * c.x;
        unsafeAtomicAdd(s0 + 0, p0.x); unsafeAtomicAdd(s0 + 1, p0.y);
        unsafeAtomicAdd(s0 + 2, p0.z); unsafeAtomicAdd(s0 + 3, p0.w);
        float* s1 = S + 4 * c.y;
        unsafeAtomicAdd(s1 + 0, p1.x); unsafeAtomicAdd(s1 + 1, p1.y);
        unsafeAtomicAdd(s1 + 2, p1.z); unsafeAtomicAdd(s1 + 3, p1.w);
    } else {
        for (int e = base; e < n_edges; ++e) {
            int r = row[e], c = col[e];
            float4 pv = p[r];
            float* s = S + 4 * c;
            unsafeAtomicAdd(s + 0, pv.x); unsafeAtomicAdd(s + 1, pv.y);
            unsafeAtomicAdd(s + 2, pv.z); unsafeAtomicAdd(s + 3, pv.w);
        }
    }
}

__global__ void k_reduce(const float4* __restrict__ S4, const float4* __restrict__ p,
                         const int* __restrict__ deg, const float* __restrict__ conv_b,
                         int n, float* __restrict__ gsum) {
    int i = blockIdx.x * blockDim.x + threadIdx.x;
    float4 v = {0.f, 0.f, 0.f, 0.f};
    if (i < n) {
        float dinv = rsqrtf((float)(deg[i] + 1));
        float4 s = S4[i];
        float4 pp = p[i];
        v.x = tanhf(dinv * (s.x + pp.x) + conv_b[0]);
        v.y = tanhf(dinv * (s.y + pp.y) + conv_b[1]);
        v.z = tanhf(dinv * (s.z + pp.z) + conv_b[2]);
        v.w = tanhf(dinv * (s.w + pp.w) + conv_b[3]);
    }
#pragma unroll
    for (int off = 32; off > 0; off >>= 1) {
        v.x += __shfl_down(v.x, off);
        v.y += __shfl_down(v.y, off);
        v.z += __shfl_down(v.z, off);
        v.w += __shfl_down(v.w, off);
    }
    __shared__ float4 lds[4];
    int lane = threadIdx.x & 63, w = threadIdx.x >> 6;
    if (lane == 0) lds[w] = v;
    __syncthreads();
    if (threadIdx.x == 0) {
        float4 tt = lds[0];
        for (int k = 1; k < 4; ++k) {
            tt.x += lds[k].x; tt.y += lds[k].y; tt.z += lds[k].z; tt.w += lds[k].w;
        }
        unsafeAtomicAdd(&gsum[0], tt.x); unsafeAtomicAdd(&gsum[1], tt.y);
        unsafeAtomicAdd(&gsum[2], tt.z); unsafeAtomicAdd(&gsum[3], tt.w);
    }
}

// ---------------- launch ----------------

extern "C" void kernel_launch(void* const* d_in, const int* in_sizes, int n_in,
                              void* d_out, int out_size, void* d_ws, size_t ws_size,
                              hipStream_t stream) {
    const float* x      = (const float*)d_in[0];
    const int*   ei     = (const int*)d_in[1];
    const float* conv_w = (const float*)d_in[2];
    const float* conv_b = (const float*)d_in[3];
    const float* fc1w   = (const float*)d_in[4];
    const float* fc1b   = (const float*)d_in[5];
    const float* fc3w   = (const float*)d_in[6];
    const float* fc3b   = (const float*)d_in[7];

    int n = in_sizes[0] / 6;
    int E = in_sizes[1] / 2;
    const int* row = ei;       // edge_index[0] = source
    const int* col = ei + E;   // edge_index[1] = target

    int P = (n + NP - 1) / NP;
    int avg = (E + P - 1) / P;
    int cap = ((avg + avg / 8 + 2048) + 15) & ~15;

    // ws layout: cursor[P] | gsum[4] | dinv[n] | ph[n] (fp16x4) | binned[P*cap]
    size_t off = 0;
    size_t cursor_off = off;          off += (size_t)P * sizeof(int);
    off = (off + 15) & ~(size_t)15;
    size_t gsum_off = off;            off += 4 * sizeof(float);
    size_t zero_end = off;
    off = (off + 15) & ~(size_t)15;
    size_t dinv_off = off;            off += (size_t)n * sizeof(float);
    off = (off + 15) & ~(size_t)15;
    size_t ph_off = off;              off += (size_t)n * sizeof(Half4);
    off = (off + 15) & ~(size_t)15;
    size_t bin_off = off;             off += (size_t)P * cap * sizeof(unsigned);
    size_t need = off;

    char* ws = (char*)d_ws;
    bool use_bin = (ws_size >= need) && (P <= NPART_MAX) && (n < (1 << 22));

    if (use_bin) {
        int* cursor = (int*)(ws + cursor_off);
        float* gsum = (float*)(ws + gsum_off);
        float* dinvg = (float*)(ws + dinv_off);
        Half4* ph = (Half4*)(ws + ph_off);
        unsigned* binned = (unsigned*)(ws + bin_off);

        hipMemsetAsync(d_ws, 0, zero_end, stream);
        int bin_blocks = (E + EPB - 1) / EPB;
        k_bin<<<bin_blocks, BINB, 0, stream>>>(row, col, E, P, cap, cursor, binned);
        k_part_node<<<P, BT, 0, stream>>>(binned, cursor, cap, x, conv_w, n, ph, dinvg);
        k_acc<<<P, BT, 0, stream>>>(binned, cursor, cap, ph, dinvg, conv_b, n, gsum);
        k_head<<<1, 64, 0, stream>>>(gsum, fc1w, fc1b, fc3w, fc3b, (float*)d_out, n);
    } else {
        size_t o = 0;
        int* deg = (int*)(ws + o);      o += (size_t)n * sizeof(int);
        o = (o + 15) & ~(size_t)15;
        float* S = (float*)(ws + o);    o += (size_t)n * 4 * sizeof(float);
        float* gsum = (float*)(ws + o);
        size_t zend = o + 4 * sizeof(float);
        o = (zend + 15) & ~(size_t)15;
        float4* p = (float4*)(ws + o);

        hipMemsetAsync(d_ws, 0, zend, stream);
        int t1 = (E + 3) / 4;
        k_deg<<<(t1 + 255) / 256, 256, 0, stream>>>(col, E, deg);
        k_node<<<(n + 255) / 256, 256, 0, stream>>>(x, conv_w, deg, p, n);
        int t3 = (E + 1) / 2;
        k_scatter<<<(t3 + 255) / 256, 256, 0, stream>>>(row, col, E, p, S);
        k_reduce<<<(n + 255) / 256, 256, 0, stream>>>((const float4*)S, p, deg, conv_b, n, gsum);
        k_head<<<1, 64, 0, stream>>>(gsum, fc1w, fc1b, fc3w, fc3b, (float*)d_out, n);
    }
}